// Round 17
// baseline (560.948 us; speedup 1.0000x reference)
//
#include <hip/hip_runtime.h>
#include <math.h>

#define Q 256

typedef unsigned short u16;
typedef unsigned int u32;
typedef __attribute__((ext_vector_type(8))) short short8;
typedef __attribute__((ext_vector_type(4))) float f32x4;

__device__ __forceinline__ float bf2f(u32 u){
  union { float f; u32 i; } v; v.i = u << 16; return v.f;
}
__device__ __forceinline__ u16 f2bf(float f){
  union { float f; u32 i; } v; v.f = f;
  u32 r = (v.i + 0x7FFFu + ((v.i >> 16) & 1u)) >> 16;
  return (u16)r;
}
__device__ __forceinline__ float softplusf(float x){
  return x > 20.f ? x : log1pf(expf(x));
}
__device__ __forceinline__ float siluf(float x){
  return x / (1.f + expf(-x));
}

__device__ __forceinline__ void gload_lds16(const void* g, const void* l){
  __builtin_amdgcn_global_load_lds(
    (const __attribute__((address_space(1))) void*)(uintptr_t)g,
    (__attribute__((address_space(3))) void*)(u32)(uintptr_t)l,
    16, 0, 0);
}

__device__ __forceinline__ u32 swz_off(int row, int col2){
  return (u32)(row*128 + (col2 ^ ((row & 7) << 4)));
}
__device__ __forceinline__ short8 frag_ld(const u16* buf, int row, int kk, int lk){
  return *(const short8*)((const char*)buf + row*128 + (((kk*4 + lk) ^ (row & 7)) << 4));
}

// Fused bf16 cast of all four inputs (one launch; group = 4 floats).
__global__ __launch_bounds__(256) void cast_all(const float* __restrict__ x,
    const float* __restrict__ w_in, const float* __restrict__ w_param,
    const float* __restrict__ w_out, u16* __restrict__ xb,
    u16* __restrict__ w_in_b, u16* __restrict__ w_param_b, u16* __restrict__ w_out_b)
{
  const size_t g = (size_t)blockIdx.x * 256 + threadIdx.x;
  const float* src; u16* dst; size_t off;
  if (g < 2097152)        { src = x;       dst = xb;        off = g; }
  else if (g < 6291456)   { src = w_in;    dst = w_in_b;    off = g - 2097152; }
  else if (g < 10518528)  { src = w_param; dst = w_param_b; off = g - 6291456; }
  else                    { src = w_out;   dst = w_out_b;   off = g - 10518528; }
  const float4 v = *(const float4*)(src + off*4);
  ushort4 o;
  o.x = f2bf(v.x); o.y = f2bf(v.y); o.z = f2bf(v.z); o.w = f2bf(v.w);
  *(ushort4*)(dst + off*4) = o;
}

// ------- 4-wave GEMM body: 128x256 tile, per-wave 128x64 -------------------
// Same proven LDS layout as the 8-wave T256 (192 rows x 128B per 24 KiB
// slice, packed row-pairs, phys chunk = logical ^ (row&7), linear gload dest
// + pre-swizzled per-lane source; 0 bank conflicts). 4 waves x (128M x 64N):
// MFMA:ds_read = 32:12 per phase (vs 16:12), 256-thread barriers.
// Regs: 128 acc + 48 frag + addr ~= 200 < 256 cap (launch_bounds(256,2)).
// NOTE r16 bug: block tile is STILL 128x256 -> grid must cover 32 m-tiles
// (2080 blocks), not 1040. Fixed here.
#define W4_STAGE(s_) \
  _Pragma("unroll") for (int q = 0; q < 6; q++) \
    gload_lds16(sptr[q] + (s_)*32, lds + (((s_)&1)*24576) + (q*256 + tid)*16);

#define W4_BODY(A_, B_, K_) \
  __shared__ char lds[49152]; \
  const int w = tid >> 6, l = tid & 63; \
  const int lr = l & 15, lk = l >> 4; \
  const u16* sptr[6]; \
  _Pragma("unroll") for (int q = 0; q < 6; q++) { \
    const int c = q*256 + tid; \
    const int r = c >> 3; \
    const int lg = (c & 7) ^ (r & 7); \
    const int lrow2 = 2*r + (lg >> 2); \
    const int kc = lg & 3; \
    sptr[q] = (lrow2 < 128) ? ((A_) + (size_t)(m0 + lrow2)*(K_) + kc*8) \
                            : ((B_) + (size_t)(n0 + (lrow2 - 128))*(K_) + kc*8); \
  } \
  const int abase = (lr >> 1)*128 + ((((lr & 1)*4 + lk) ^ ((lr >> 1) & 7)) << 4); \
  const int brow0 = 64 + ((w*64 + lr) >> 1); \
  const int bbase = brow0*128 + ((((lr & 1)*4 + lk) ^ (brow0 & 7)) << 4); \
  f32x4 acc[8][4]; \
  { f32x4 z = {0.f,0.f,0.f,0.f}; \
    _Pragma("unroll") for (int m = 0; m < 8; m++) \
    _Pragma("unroll") for (int n = 0; n < 4; n++) acc[m][n] = z; } \
  W4_STAGE(0) \
  asm volatile("s_waitcnt vmcnt(0)" ::: "memory"); \
  __builtin_amdgcn_s_barrier(); \
  { const int NS = (K_)/32; \
    for (int s = 0; s < NS-1; ++s) { \
      const char* sb_ = lds + ((s & 1)*24576); \
      short8 aF[8], bF[4]; \
      W4_STAGE(s+1) \
      _Pragma("unroll") for (int m = 0; m < 8; m++) \
        aF[m] = *(const short8*)(sb_ + abase + m*1024); \
      _Pragma("unroll") for (int n = 0; n < 4; n++) \
        bF[n] = *(const short8*)(sb_ + bbase + n*1024); \
      __builtin_amdgcn_s_setprio(1); \
      _Pragma("unroll") for (int m = 0; m < 8; m++) \
      _Pragma("unroll") for (int n = 0; n < 4; n++) \
        acc[m][n] = __builtin_amdgcn_mfma_f32_16x16x32_bf16(aF[m], bF[n], acc[m][n], 0, 0, 0); \
      __builtin_amdgcn_s_setprio(0); \
      asm volatile("s_waitcnt vmcnt(0)" ::: "memory"); \
      __builtin_amdgcn_s_barrier(); \
    } \
    { const char* sb_ = lds + (((K_)/32 - 1) & 1)*24576; \
      short8 aF[8], bF[4]; \
      _Pragma("unroll") for (int m = 0; m < 8; m++) \
        aF[m] = *(const short8*)(sb_ + abase + m*1024); \
      _Pragma("unroll") for (int n = 0; n < 4; n++) \
        bF[n] = *(const short8*)(sb_ + bbase + n*1024); \
      _Pragma("unroll") for (int m = 0; m < 8; m++) \
      _Pragma("unroll") for (int n = 0; n < 4; n++) \
        acc[m][n] = __builtin_amdgcn_mfma_f32_16x16x32_bf16(aF[m], bF[n], acc[m][n], 0, 0, 0); \
    } \
  }

// Fused in-proj + param-proj: one 2080-block stream of 256-thread blocks.
// wg < 1024: in-proj (32m x 32n); wg >= 1024: param (32m x 33n padded).
__global__ void __launch_bounds__(256, 2) gemm_inpar(const u16* __restrict__ A,
    const u16* __restrict__ Bin, const u16* __restrict__ Bpar,
    u16* __restrict__ inp, u16* __restrict__ resb,
    float* __restrict__ dtb, u16* __restrict__ Bb, u16* __restrict__ Cb)
{
  const int tid = threadIdx.x;
  const int nwg = gridDim.x, bid = blockIdx.x;
  const int wg = (bid & 7) * (nwg >> 3) + (bid >> 3);
  const bool isPar = (wg >= 1024);
  int m0, n0;
  const u16* Bmat;
  if (!isPar) { Bmat = Bin;  m0 = (wg >> 5) * 128;   n0 = (wg & 31) * 256; }
  else        { Bmat = Bpar; const int w2 = wg - 1024;
                m0 = (w2 / 33) * 128;                 n0 = (w2 % 33) * 256; }
  W4_BODY(A, Bmat, 2048)
  if (!isPar) {
    #pragma unroll
    for (int m = 0; m < 8; m++)
      #pragma unroll
      for (int n = 0; n < 4; n++) {
        const int col = n0 + w*64 + n*16 + lr;
        #pragma unroll
        for (int j = 0; j < 4; j++) {
          const int row = m0 + m*16 + lk*4 + j;
          const u16 v = f2bf(acc[m][n][j]);
          if (col < 4096) inp[(size_t)row*4096 + col] = v;
          else            resb[(size_t)row*4096 + (col - 4096)] = v;
        }
      }
  } else {
    #pragma unroll
    for (int m = 0; m < 8; m++)
      #pragma unroll
      for (int n = 0; n < 4; n++) {
        const int col = n0 + w*64 + n*16 + lr;
        if (col < 8256) {
          const int h = col / 129, rr = col - h*129;
          #pragma unroll
          for (int j = 0; j < 4; j++) {
            const int row = m0 + m*16 + lk*4 + j;
            const float v = acc[m][n][j];
            if (rr == 0)      dtb[(size_t)row*64 + h] = v;
            else if (rr < 65) Bb[((size_t)row*64 + h)*64 + (rr-1)]  = f2bf(v);
            else              Cb[((size_t)row*64 + h)*64 + (rr-65)] = f2bf(v);
          }
        }
      }
  }
}

// ------------- gemm_out: 128x128 tile, K-step 64 double-buffer -------------
#define O128_STAGE(s_) \
  _Pragma("unroll") for (int q = 0; q < 4; q++) \
    gload_lds16(sptr[q] + (s_)*64, lds + (((s_)&1)*32768) + (q*512 + tid)*16);

__global__ void __launch_bounds__(512, 4) void_dummy();
__global__ void __launch_bounds__(512, 4) gemm_out64(const u16* __restrict__ A,
    const u16* __restrict__ B, float* __restrict__ C)
{
  __shared__ char lds[65536];
  const int tid = threadIdx.x;
  const int nwg = gridDim.x, bid = blockIdx.x;
  const int wg = (bid & 7) * (nwg >> 3) + (bid >> 3);
  const int m0 = (wg >> 4) * 128, n0 = (wg & 15) * 128;
  const int w = tid >> 6, l = tid & 63;
  const int wr = w >> 2, wc = w & 3;
  const int lr = l & 15, lk = l >> 4;
  const u16* sptr[4];
  #pragma unroll
  for (int q = 0; q < 4; q++) {
    const int c = q*512 + tid;
    const int r = c >> 3;
    const int jl = (c & 7) ^ (r & 7);
    sptr[q] = (r < 128) ? (A + (size_t)(m0 + r)*4096 + jl*8)
                        : (B + (size_t)(n0 + (r - 128))*4096 + jl*8);
  }
  const int ko0 = ((lk       ^ (lr & 7)) << 4);
  const int ko1 = (((4 + lk) ^ (lr & 7)) << 4);
  const int abase = (wr*64 + lr) * 128;
  const int bbase = (128 + wc*32 + lr) * 128;
  f32x4 acc[4][2];
  { f32x4 z = {0.f,0.f,0.f,0.f};
    #pragma unroll
    for (int m = 0; m < 4; m++)
      #pragma unroll
      for (int n = 0; n < 2; n++) acc[m][n] = z; }
  O128_STAGE(0)
  asm volatile("s_waitcnt vmcnt(0)" ::: "memory");
  __builtin_amdgcn_s_barrier();
  for (int s = 0; s < 63; ++s) {
    const char* sb_ = lds + ((s & 1)*32768);
    short8 aF[2][4], bF[2][2];
    O128_STAGE(s+1)
    #pragma unroll
    for (int m = 0; m < 4; m++) {
      aF[0][m] = *(const short8*)(sb_ + abase + m*2048 + ko0);
      aF[1][m] = *(const short8*)(sb_ + abase + m*2048 + ko1);
    }
    #pragma unroll
    for (int n = 0; n < 2; n++) {
      bF[0][n] = *(const short8*)(sb_ + bbase + n*2048 + ko0);
      bF[1][n] = *(const short8*)(sb_ + bbase + n*2048 + ko1);
    }
    __builtin_amdgcn_s_setprio(1);
    #pragma unroll
    for (int m = 0; m < 4; m++)
      #pragma unroll
      for (int n = 0; n < 2; n++)
        #pragma unroll
        for (int kk = 0; kk < 2; kk++)
          acc[m][n] = __builtin_amdgcn_mfma_f32_16x16x32_bf16(aF[kk][m], bF[kk][n], acc[m][n], 0, 0, 0);
    __builtin_amdgcn_s_setprio(0);
    asm volatile("s_waitcnt vmcnt(0)" ::: "memory");
    __builtin_amdgcn_s_barrier();
  }
  {
    const char* sb_ = lds + ((63 & 1)*32768);
    short8 aF[2][4], bF[2][2];
    #pragma unroll
    for (int m = 0; m < 4; m++) {
      aF[0][m] = *(const short8*)(sb_ + abase + m*2048 + ko0);
      aF[1][m] = *(const short8*)(sb_ + abase + m*2048 + ko1);
    }
    #pragma unroll
    for (int n = 0; n < 2; n++) {
      bF[0][n] = *(const short8*)(sb_ + bbase + n*2048 + ko0);
      bF[1][n] = *(const short8*)(sb_ + bbase + n*2048 + ko1);
    }
    #pragma unroll
    for (int m = 0; m < 4; m++)
      #pragma unroll
      for (int n = 0; n < 2; n++)
        #pragma unroll
        for (int kk = 0; kk < 2; kk++)
          acc[m][n] = __builtin_amdgcn_mfma_f32_16x16x32_bf16(aF[kk][m], bF[kk][n], acc[m][n], 0, 0, 0);
  }
  #pragma unroll
  for (int m = 0; m < 4; m++)
    #pragma unroll
    for (int n = 0; n < 2; n++) {
      const int col = n0 + wc*32 + n*16 + lr;
      #pragma unroll
      for (int j = 0; j < 4; j++)
        C[(size_t)(m0 + wr*64 + m*16 + lk*4 + j)*2048 + col] = acc[m][n][j];
    }
}

// ---------------- SSD ------------------------------------------------------
__global__ __launch_bounds__(256) void ssd_phaseA(const float* __restrict__ dtb,
    const u16* __restrict__ Bb, const u16* __restrict__ inp,
    float* __restrict__ cs_g, float* __restrict__ achunk, float* __restrict__ states_t)
{
  const int g = blockIdx.x, tid = threadIdx.x;
  const int p = g * Q + tid;
  __shared__ float sc[Q];
  __shared__ u16 sBt[64*64];
  __shared__ u16 sXt[64*64];
  sc[tid] = -softplusf(dtb[p]);
  __syncthreads();
  for (int off = 1; off < Q; off <<= 1) {
    float v = (tid >= off) ? sc[tid - off] : 0.f;
    __syncthreads();
    if (tid >= off) sc[tid] += v;
    __syncthreads();
  }
  cs_g[p] = sc[tid];
  const float cl = sc[Q-1];
  if (tid == 0) achunk[g] = expf(cl);

  const int w = tid >> 6, l = tid & 63;
  const int lrow = l & 15, lk = l >> 4;
  const int tj = tid & 63, tcb = (tid >> 6) * 16;
  f32x4 acc[4];
  { f32x4 z = {0,0,0,0}; acc[0]=z; acc[1]=z; acc[2]=z; acc[3]=z; }

  for (int js = 0; js < 4; js++) {
    __syncthreads();
    {
      const int jc = js*64 + tj;
      const float wj = expf(cl - sc[jc]);
      const size_t prow = ((size_t)g*Q + jc) * 64;
      union { uint4 v; u16 s[8]; } b0, b1, x0, x1;
      b0.v = *(const uint4*)&Bb[prow + tcb];
      b1.v = *(const uint4*)&Bb[prow + tcb + 8];
      x0.v = *(const uint4*)&inp[prow + tcb];
      x1.v = *(const uint4*)&inp[prow + tcb + 8];
      #pragma unroll
      for (int q = 0; q < 8; q++) {
        const int r0 = tcb + q, r1 = tcb + 8 + q;
        *(u16*)((char*)sBt + swz_off(r0, 2*tj)) = f2bf(wj * bf2f((u32)b0.s[q]));
        *(u16*)((char*)sBt + swz_off(r1, 2*tj)) = f2bf(wj * bf2f((u32)b1.s[q]));
        *(u16*)((char*)sXt + swz_off(r0, 2*tj)) = x0.s[q];
        *(u16*)((char*)sXt + swz_off(r1, 2*tj)) = x1.s[q];
      }
    }
    __syncthreads();
    short8 aX0 = frag_ld(sXt, w*16 + lrow, 0, lk);
    short8 aX1 = frag_ld(sXt, w*16 + lrow, 1, lk);
    #pragma unroll
    for (int n = 0; n < 4; n++) {
      short8 b0 = frag_ld(sBt, n*16 + lrow, 0, lk);
      short8 b1 = frag_ld(sBt, n*16 + lrow, 1, lk);
      acc[n] = __builtin_amdgcn_mfma_f32_16x16x32_bf16(aX0, b0, acc[n], 0, 0, 0);
      acc[n] = __builtin_amdgcn_mfma_f32_16x16x32_bf16(aX1, b1, acc[n], 0, 0, 0);
    }
  }
  #pragma unroll
  for (int reg = 0; reg < 4; reg++) {
    const int d = w*16 + lk*4 + reg;
    #pragma unroll
    for (int n = 0; n < 4; n++)
      states_t[(size_t)g*4096 + d*64 + n*16 + lrow] = acc[n][reg];
  }
}

__global__ __launch_bounds__(256) void ssd_scan(float* __restrict__ states,
    const float* __restrict__ achunk)
{
  const int n = blockIdx.x, tid = threadIdx.x;
  float S[16];
  #pragma unroll
  for (int k = 0; k < 16; k++) S[k] = 0.f;
  for (int c = 0; c < 16; c++) {
    const int g = n*16 + c;
    const float A = achunk[g];
    #pragma unroll
    for (int k = 0; k < 16; k++) {
      const size_t e = (size_t)g * 4096 + tid + k*256;
      const float st = states[e];
      states[e] = S[k];
      S[k] = fmaf(A, S[k], st);
    }
  }
}

__global__ __launch_bounds__(256) void ssd_diag(const u16* __restrict__ Bb,
    const u16* __restrict__ Cb, const u16* __restrict__ inp,
    const float* __restrict__ cs_g, const float* __restrict__ states_t,
    const u16* __restrict__ resb, u16* __restrict__ yb)
{
  const int g = blockIdx.y, it = blockIdx.x, tid = threadIdx.x;
  const int w = tid >> 6, l = tid & 63;
  const int lrow = l & 15, lk = l >> 4;
  const int p_base = g * Q;
  __shared__ u16 sC[64*64];
  __shared__ u16 sB[64*64];
  __shared__ u16 sX[64*64];
  __shared__ u16 sP[64*64];
  __shared__ float csi[64], csj[64];

  const int r = tid >> 2, c0 = (tid & 3) << 4;
  {
    const size_t prow = (size_t)(p_base + it*64 + r) * 64;
    uint4 v0 = *(const uint4*)&Cb[prow + c0];
    uint4 v1 = *(const uint4*)&Cb[prow + c0 + 8];
    *(uint4*)((char*)sC + swz_off(r, c0*2))      = v0;
    *(uint4*)((char*)sC + swz_off(r, c0*2 + 16)) = v1;
    if (tid < 64) csi[tid] = cs_g[p_base + it*64 + tid];
  }
  const int i0 = w * 16;
  const int xj = tid & 63, xdb = (tid >> 6) * 16;
  f32x4 accY[4];
  { f32x4 z = {0,0,0,0}; accY[0]=z; accY[1]=z; accY[2]=z; accY[3]=z; }

  for (int jt = 0; jt <= it; jt++) {
    __syncthreads();
    {
      const size_t prow = (size_t)(p_base + jt*64 + r) * 64;
      uint4 v0 = *(const uint4*)&Bb[prow + c0];
      uint4 v1 = *(const uint4*)&Bb[prow + c0 + 8];
      *(uint4*)((char*)sB + swz_off(r, c0*2))      = v0;
      *(uint4*)((char*)sB + swz_off(r, c0*2 + 16)) = v1;
      if (tid < 64) csj[tid] = cs_g[p_base + jt*64 + tid];
    }
    {
      const size_t prow = (size_t)(p_base + jt*64 + xj) * 64;
      union { uint4 v; u16 s[8]; } x0, x1;
      x0.v = *(const uint4*)&inp[prow + xdb];
      x1.v = *(const uint4*)&inp[prow + xdb + 8];
      #pragma unroll
      for (int q = 0; q < 8; q++) {
        *(u16*)((char*)sX + swz_off(xdb + q,     2*xj)) = x0.s[q];
        *(u16*)((char*)sX + swz_off(xdb + 8 + q, 2*xj)) = x1.s[q];
      }
    }
    __syncthreads();
    f32x4 sAcc[4];
    { f32x4 z = {0,0,0,0}; sAcc[0]=z; sAcc[1]=z; sAcc[2]=z; sAcc[3]=z; }
    {
      short8 aC0 = frag_ld(sC, i0 + lrow, 0, lk);
      short8 aC1 = frag_ld(sC, i0 + lrow, 1, lk);
      #pragma unroll
      for (int n = 0; n < 4; n++) {
        short8 b0 = frag_ld(sB, n*16 + lrow, 0, lk);
        short8 b1 = frag_ld(sB, n*16 + lrow, 1, lk);
        sAcc[n] = __builtin_amdgcn_mfma_f32_16x16x32_bf16(aC0, b0, sAcc[n], 0, 0, 0);
        sAcc[n] = __builtin_amdgcn_mfma_f32_16x16x32_bf16(aC1, b1, sAcc[n], 0, 0, 0);
      }
    }
    const bool full = (jt < it);
    #pragma unroll
    for (int n = 0; n < 4; n++) {
      const int j_l = n*16 + lrow;
      const float cj = csj[j_l];
      #pragma unroll
      for (int reg = 0; reg < 4; reg++) {
        const int i_l = i0 + lk*4 + reg;
        float s = 0.f;
        if (full || j_l <= i_l) s = sAcc[n][reg] * expf(csi[i_l] - cj);
        *(u16*)((char*)sP + swz_off(i_l, n*32 + 2*lrow)) = f2bf(s);
      }
    }
    {
      short8 aP0 = frag_ld(sP, i0 + lrow, 0, lk);
      short8 aP1 = frag_ld(sP, i0 + lrow, 1, lk);
      #pragma unroll
      for (int n = 0; n < 4; n++) {
        short8 x0f = frag_ld(sX, n*16 + lrow, 0, lk);
        short8 x1f = frag_ld(sX, n*16 + lrow, 1, lk);
        accY[n] = __builtin_amdgcn_mfma_f32_16x16x32_bf16(aP0, x0f, accY[n], 0, 0, 0);
        accY[n] = __builtin_amdgcn_mfma_f32_16x16x32_bf16(aP1, x1f, accY[n], 0, 0, 0);
      }
    }
  }
  __syncthreads();
  {
    const int d = tid & 63, sb = (tid >> 6) * 16;
    const float* srow = &states_t[(size_t)g*4096 + d*64 + sb];
    float4 f0 = *(const float4*)(srow);
    float4 f1 = *(const float4*)(srow + 4);
    float4 f2 = *(const float4*)(srow + 8);
    float4 f3 = *(const float4*)(srow + 12);
    union { uint4 v; u16 s[8]; } o0, o1;
    o0.s[0]=f2bf(f0.x); o0.s[1]=f2bf(f0.y); o0.s[2]=f2bf(f0.z); o0.s[3]=f2bf(f0.w);
    o0.s[4]=f2bf(f1.x); o0.s[5]=f2bf(f1.y); o0.s[6]=f2bf(f1.z); o0.s[7]=f2bf(f1.w);
    o1.s[0]=f2bf(f2.x); o1.s[1]=f2bf(f2.y); o1.s[2]=f2bf(f2.z); o1.s[3]=f2bf(f2.w);
    o1.s[4]=f2bf(f3.x); o1.s[5]=f2bf(f3.y); o1.s[6]=f2bf(f3.z); o1.s[7]=f2bf(f3.w);
    *(uint4*)((char*)sB + swz_off(d, sb*2))      = o0.v;
    *(uint4*)((char*)sB + swz_off(d, sb*2 + 16)) = o1.v;
  }
  __syncthreads();
  f32x4 accI[4];
  { f32x4 z = {0,0,0,0}; accI[0]=z; accI[1]=z; accI[2]=z; accI[3]=z; }
  {
    short8 aC0 = frag_ld(sC, i0 + lrow, 0, lk);
    short8 aC1 = frag_ld(sC, i0 + lrow, 1, lk);
    #pragma unroll
    for (int n = 0; n < 4; n++) {
      short8 s0 = frag_ld(sB, n*16 + lrow, 0, lk);
      short8 s1 = frag_ld(sB, n*16 + lrow, 1, lk);
      accI[n] = __builtin_amdgcn_mfma_f32_16x16x32_bf16(aC0, s0, accI[n], 0, 0, 0);
      accI[n] = __builtin_amdgcn_mfma_f32_16x16x32_bf16(aC1, s1, accI[n], 0, 0, 0);
    }
  }
  #pragma unroll
  for (int reg = 0; reg < 4; reg++) {
    const int i_l = i0 + lk*4 + reg;
    const float ei = expf(csi[i_l]);
    const size_t prow = (size_t)(p_base + it*64 + i_l) * 64;
    #pragma unroll
    for (int n = 0; n < 4; n++) {
      const int d = n*16 + lrow;
      const float yv = accY[n][reg] + ei * accI[n][reg];
      const float rv = bf2f((u32)resb[prow + d]);
      yb[prow + d] = f2bf(yv * siluf(rv));
    }
  }
}

extern "C" void kernel_launch(void* const* d_in, const int* in_sizes, int n_in,
                              void* d_out, int out_size, void* d_ws, size_t ws_size,
                              hipStream_t stream)
{
  const float* x       = (const float*)d_in[0];
  const float* w_in    = (const float*)d_in[1];
  const float* w_param = (const float*)d_in[2];
  const float* w_out   = (const float*)d_in[3];
  float* out = (float*)d_out;
  char* ws = (char*)d_ws;

  float* states    = (float*)(ws);                 // 16 MiB (aliases xb)
  u16*   xb        = (u16*)  (ws);                 // 16 MiB
  u16*   yb        = (u16*)  (ws + 0x1000000ull);  // 32 MiB (aliases w_in_b)
  u16*   w_in_b    = (u16*)  (ws + 0x1000000ull);  // 32 MiB
  u16*   w_param_b = (u16*)  (ws + 0x3000000ull);  // 8448*2048*2 = 33 MiB (pad rows)
  u16*   w_out_b   = (u16*)  (ws + 0x5100000ull);  // 16 MiB
  u16*   inp       = (u16*)  (ws + 0x6100000ull);  // 32 MiB
  u16*   resb      = (u16*)  (ws + 0x8100000ull);  // 32 MiB
  u16*   Bb        = (u16*)  (ws + 0xA100000ull);  // 32 MiB
  u16*   Cb        = (u16*)  (ws + 0xC100000ull);  // 32 MiB
  float* dtb       = (float*)(ws + 0xE100000ull);  // 1 MiB
  float* cs        = (float*)(ws + 0xE200000ull);  // 1 MiB
  float* achunk    = (float*)(ws + 0xE300000ull);  // 4 KiB

  cast_all<<<49280, 256, 0, stream>>>(x, w_in, w_param, w_out,
                                      xb, w_in_b, w_param_b, w_out_b);

  gemm_inpar<<<2080, 256, 0, stream>>>(xb, w_in_b, w_param_b,
                                       inp, resb, dtb, Bb, Cb);
  ssd_phaseA<<<1024, 256, 0, stream>>>(dtb, Bb, inp, cs, achunk, states);
  ssd_scan<<<64, 256, 0, stream>>>(states, achunk);
  ssd_diag<<<dim3(4, 1024), 256, 0, stream>>>(Bb, Cb, inp, cs, states, resb, yb);
  gemm_out64<<<512, 512, 0, stream>>>(yb, w_out_b, out);
}

// Round 18
// 547.626 us; speedup vs baseline: 1.0243x; 1.0243x over previous
//
#include <hip/hip_runtime.h>
#include <math.h>

#define Q 256

typedef unsigned short u16;
typedef unsigned int u32;
typedef __attribute__((ext_vector_type(8))) short short8;
typedef __attribute__((ext_vector_type(4))) float f32x4;

__device__ __forceinline__ float bf2f(u32 u){
  union { float f; u32 i; } v; v.i = u << 16; return v.f;
}
__device__ __forceinline__ u16 f2bf(float f){
  union { float f; u32 i; } v; v.f = f;
  u32 r = (v.i + 0x7FFFu + ((v.i >> 16) & 1u)) >> 16;
  return (u16)r;
}
__device__ __forceinline__ float softplusf(float x){
  return x > 20.f ? x : log1pf(expf(x));
}
__device__ __forceinline__ float siluf(float x){
  return x / (1.f + expf(-x));
}

__device__ __forceinline__ void gload_lds16(const void* g, const void* l){
  __builtin_amdgcn_global_load_lds(
    (const __attribute__((address_space(1))) void*)(uintptr_t)g,
    (__attribute__((address_space(3))) void*)(u32)(uintptr_t)l,
    16, 0, 0);
}

__device__ __forceinline__ u32 swz_off(int row, int col2){
  return (u32)(row*128 + (col2 ^ ((row & 7) << 4)));
}
__device__ __forceinline__ short8 frag_ld(const u16* buf, int row, int kk, int lk){
  return *(const short8*)((const char*)buf + row*128 + (((kk*4 + lk) ^ (row & 7)) << 4));
}

// Fused bf16 cast of all four inputs (one launch; group = 4 floats).
__global__ __launch_bounds__(256) void cast_all(const float* __restrict__ x,
    const float* __restrict__ w_in, const float* __restrict__ w_param,
    const float* __restrict__ w_out, u16* __restrict__ xb,
    u16* __restrict__ w_in_b, u16* __restrict__ w_param_b, u16* __restrict__ w_out_b)
{
  const size_t g = (size_t)blockIdx.x * 256 + threadIdx.x;
  const float* src; u16* dst; size_t off;
  if (g < 2097152)        { src = x;       dst = xb;        off = g; }
  else if (g < 6291456)   { src = w_in;    dst = w_in_b;    off = g - 2097152; }
  else if (g < 10518528)  { src = w_param; dst = w_param_b; off = g - 6291456; }
  else                    { src = w_out;   dst = w_out_b;   off = g - 10518528; }
  const float4 v = *(const float4*)(src + off*4);
  ushort4 o;
  o.x = f2bf(v.x); o.y = f2bf(v.y); o.z = f2bf(v.z); o.w = f2bf(v.w);
  *(ushort4*)(dst + off*4) = o;
}

// ------------- TLP GEMM body: 128x256 tile, 8 waves, 2 blocks/CU -----------
// Session-best configuration (r14/r15): 124 regs/thread (60 VGPR + 64 acc),
// 4 waves/SIMD, 37% MfmaUtil. Wave-shape A/B (r17): 4-wave 128x64/wave costs
// 236 regs -> occupancy halves, 352 us vs 338 us. Keep 8-wave.
#define T256_STAGE(s_) \
  _Pragma("unroll") for (int q = 0; q < 3; q++) \
    gload_lds16(sptr[q] + (s_)*32, lds + (((s_)&1)*24576) + (q*512 + tid)*16);

#define T256_BODY(A_, B_, K_) \
  __shared__ char lds[49152]; \
  const int w = tid >> 6, l = tid & 63; \
  const int wr = w >> 2, wc = w & 3; \
  const int lr = l & 15, lk = l >> 4; \
  const u16* sptr[3]; \
  _Pragma("unroll") for (int q = 0; q < 3; q++) { \
    const int c = q*512 + tid; \
    const int r = c >> 3; \
    const int lg = (c & 7) ^ (r & 7); \
    const int lrow2 = 2*r + (lg >> 2); \
    const int kc = lg & 3; \
    sptr[q] = (lrow2 < 128) ? ((A_) + (size_t)(m0 + lrow2)*(K_) + kc*8) \
                            : ((B_) + (size_t)(n0 + (lrow2 - 128))*(K_) + kc*8); \
  } \
  const int arow0 = wr*64 + lr; \
  const int abrow = arow0 >> 1; \
  const int abase = abrow*128 + ((((arow0 & 1)*4 + lk) ^ (abrow & 7)) << 4); \
  const int brow0 = 64 + ((wc*64 + lr) >> 1); \
  const int bbase = brow0*128 + ((((lr & 1)*4 + lk) ^ (brow0 & 7)) << 4); \
  f32x4 acc[4][4]; \
  { f32x4 z = {0.f,0.f,0.f,0.f}; \
    _Pragma("unroll") for (int m = 0; m < 4; m++) \
    _Pragma("unroll") for (int n = 0; n < 4; n++) acc[m][n] = z; } \
  T256_STAGE(0) \
  asm volatile("s_waitcnt vmcnt(0)" ::: "memory"); \
  __builtin_amdgcn_s_barrier(); \
  { const int NS = (K_)/32; \
    for (int s = 0; s < NS-1; ++s) { \
      const char* sb_ = lds + ((s & 1)*24576); \
      short8 aF[4], bF[4]; \
      T256_STAGE(s+1) \
      _Pragma("unroll") for (int m = 0; m < 4; m++) \
        aF[m] = *(const short8*)(sb_ + abase + m*1024); \
      _Pragma("unroll") for (int n = 0; n < 4; n++) \
        bF[n] = *(const short8*)(sb_ + bbase + n*1024); \
      __builtin_amdgcn_s_setprio(1); \
      _Pragma("unroll") for (int m = 0; m < 4; m++) \
      _Pragma("unroll") for (int n = 0; n < 4; n++) \
        acc[m][n] = __builtin_amdgcn_mfma_f32_16x16x32_bf16(aF[m], bF[n], acc[m][n], 0, 0, 0); \
      __builtin_amdgcn_s_setprio(0); \
      asm volatile("s_waitcnt vmcnt(0)" ::: "memory"); \
      __builtin_amdgcn_s_barrier(); \
    } \
    { const char* sb_ = lds + (((K_)/32 - 1) & 1)*24576; \
      short8 aF[4], bF[4]; \
      _Pragma("unroll") for (int m = 0; m < 4; m++) \
        aF[m] = *(const short8*)(sb_ + abase + m*1024); \
      _Pragma("unroll") for (int n = 0; n < 4; n++) \
        bF[n] = *(const short8*)(sb_ + bbase + n*1024); \
      _Pragma("unroll") for (int m = 0; m < 4; m++) \
      _Pragma("unroll") for (int n = 0; n < 4; n++) \
        acc[m][n] = __builtin_amdgcn_mfma_f32_16x16x32_bf16(aF[m], bF[n], acc[m][n], 0, 0, 0); \
    } \
  }

// Fused in-proj + param-proj: one 2080-block stream.
// wg < 1024: in-proj tile (32 N-tiles of w_in);
// wg >= 1024: param tile (33 N-tiles of padded w_param, cols >= 8256 dropped).
__global__ void __launch_bounds__(512, 4) gemm_inpar(const u16* __restrict__ A,
    const u16* __restrict__ Bin, const u16* __restrict__ Bpar,
    u16* __restrict__ inp, u16* __restrict__ resb,
    float* __restrict__ dtb, u16* __restrict__ Bb, u16* __restrict__ Cb)
{
  const int tid = threadIdx.x;
  const int nwg = gridDim.x, bid = blockIdx.x;
  const int wg = (bid & 7) * (nwg >> 3) + (bid >> 3);
  const bool isPar = (wg >= 1024);
  int m0, n0;
  const u16* Bmat;
  if (!isPar) { Bmat = Bin;  m0 = (wg >> 5) * 128;        n0 = (wg & 31) * 256; }
  else        { Bmat = Bpar; const int w2 = wg - 1024;
                m0 = (w2 / 33) * 128;                      n0 = (w2 % 33) * 256; }
  T256_BODY(A, Bmat, 2048)
  if (!isPar) {
    #pragma unroll
    for (int m = 0; m < 4; m++)
      #pragma unroll
      for (int n = 0; n < 4; n++) {
        const int col = n0 + wc*64 + n*16 + lr;
        #pragma unroll
        for (int j = 0; j < 4; j++) {
          const int row = m0 + wr*64 + m*16 + lk*4 + j;
          const u16 v = f2bf(acc[m][n][j]);
          if (col < 4096) inp[(size_t)row*4096 + col] = v;
          else            resb[(size_t)row*4096 + (col - 4096)] = v;
        }
      }
  } else {
    #pragma unroll
    for (int m = 0; m < 4; m++)
      #pragma unroll
      for (int n = 0; n < 4; n++) {
        const int col = n0 + wc*64 + n*16 + lr;
        if (col < 8256) {
          const int h = col / 129, rr = col - h*129;
          #pragma unroll
          for (int j = 0; j < 4; j++) {
            const int row = m0 + wr*64 + m*16 + lk*4 + j;
            const float v = acc[m][n][j];
            if (rr == 0)      dtb[(size_t)row*64 + h] = v;
            else if (rr < 65) Bb[((size_t)row*64 + h)*64 + (rr-1)]  = f2bf(v);
            else              Cb[((size_t)row*64 + h)*64 + (rr-65)] = f2bf(v);
          }
        }
      }
  }
}

// ------------- gemm_out: 128x128 tile, K-step 64 double-buffer -------------
#define O128_STAGE(s_) \
  _Pragma("unroll") for (int q = 0; q < 4; q++) \
    gload_lds16(sptr[q] + (s_)*64, lds + (((s_)&1)*32768) + (q*512 + tid)*16);

__global__ void __launch_bounds__(512, 4) gemm_out64(const u16* __restrict__ A,
    const u16* __restrict__ B, float* __restrict__ C)
{
  __shared__ char lds[65536];
  const int tid = threadIdx.x;
  const int nwg = gridDim.x, bid = blockIdx.x;
  const int wg = (bid & 7) * (nwg >> 3) + (bid >> 3);
  const int m0 = (wg >> 4) * 128, n0 = (wg & 15) * 128;
  const int w = tid >> 6, l = tid & 63;
  const int wr = w >> 2, wc = w & 3;
  const int lr = l & 15, lk = l >> 4;
  const u16* sptr[4];
  #pragma unroll
  for (int q = 0; q < 4; q++) {
    const int c = q*512 + tid;
    const int r = c >> 3;
    const int jl = (c & 7) ^ (r & 7);
    sptr[q] = (r < 128) ? (A + (size_t)(m0 + r)*4096 + jl*8)
                        : (B + (size_t)(n0 + (r - 128))*4096 + jl*8);
  }
  const int ko0 = ((lk       ^ (lr & 7)) << 4);
  const int ko1 = (((4 + lk) ^ (lr & 7)) << 4);
  const int abase = (wr*64 + lr) * 128;
  const int bbase = (128 + wc*32 + lr) * 128;
  f32x4 acc[4][2];
  { f32x4 z = {0.f,0.f,0.f,0.f};
    #pragma unroll
    for (int m = 0; m < 4; m++)
      #pragma unroll
      for (int n = 0; n < 2; n++) acc[m][n] = z; }
  O128_STAGE(0)
  asm volatile("s_waitcnt vmcnt(0)" ::: "memory");
  __builtin_amdgcn_s_barrier();
  for (int s = 0; s < 63; ++s) {
    const char* sb_ = lds + ((s & 1)*32768);
    short8 aF[2][4], bF[2][2];
    O128_STAGE(s+1)
    #pragma unroll
    for (int m = 0; m < 4; m++) {
      aF[0][m] = *(const short8*)(sb_ + abase + m*2048 + ko0);
      aF[1][m] = *(const short8*)(sb_ + abase + m*2048 + ko1);
    }
    #pragma unroll
    for (int n = 0; n < 2; n++) {
      bF[0][n] = *(const short8*)(sb_ + bbase + n*2048 + ko0);
      bF[1][n] = *(const short8*)(sb_ + bbase + n*2048 + ko1);
    }
    __builtin_amdgcn_s_setprio(1);
    #pragma unroll
    for (int m = 0; m < 4; m++)
      #pragma unroll
      for (int n = 0; n < 2; n++)
        #pragma unroll
        for (int kk = 0; kk < 2; kk++)
          acc[m][n] = __builtin_amdgcn_mfma_f32_16x16x32_bf16(aF[kk][m], bF[kk][n], acc[m][n], 0, 0, 0);
    __builtin_amdgcn_s_setprio(0);
    asm volatile("s_waitcnt vmcnt(0)" ::: "memory");
    __builtin_amdgcn_s_barrier();
  }
  {
    const char* sb_ = lds + ((63 & 1)*32768);
    short8 aF[2][4], bF[2][2];
    #pragma unroll
    for (int m = 0; m < 4; m++) {
      aF[0][m] = *(const short8*)(sb_ + abase + m*2048 + ko0);
      aF[1][m] = *(const short8*)(sb_ + abase + m*2048 + ko1);
    }
    #pragma unroll
    for (int n = 0; n < 2; n++) {
      bF[0][n] = *(const short8*)(sb_ + bbase + n*2048 + ko0);
      bF[1][n] = *(const short8*)(sb_ + bbase + n*2048 + ko1);
    }
    #pragma unroll
    for (int m = 0; m < 4; m++)
      #pragma unroll
      for (int n = 0; n < 2; n++)
        #pragma unroll
        for (int kk = 0; kk < 2; kk++)
          acc[m][n] = __builtin_amdgcn_mfma_f32_16x16x32_bf16(aF[kk][m], bF[kk][n], acc[m][n], 0, 0, 0);
  }
  #pragma unroll
  for (int m = 0; m < 4; m++)
    #pragma unroll
    for (int n = 0; n < 2; n++) {
      const int col = n0 + wc*32 + n*16 + lr;
      #pragma unroll
      for (int j = 0; j < 4; j++)
        C[(size_t)(m0 + wr*64 + m*16 + lk*4 + j)*2048 + col] = acc[m][n][j];
    }
}

// ---------------- SSD ------------------------------------------------------
__global__ __launch_bounds__(256) void ssd_phaseA(const float* __restrict__ dtb,
    const u16* __restrict__ Bb, const u16* __restrict__ inp,
    float* __restrict__ cs_g, float* __restrict__ achunk, float* __restrict__ states_t)
{
  const int g = blockIdx.x, tid = threadIdx.x;
  const int p = g * Q + tid;
  __shared__ float sc[Q];
  __shared__ u16 sBt[64*64];
  __shared__ u16 sXt[64*64];
  sc[tid] = -softplusf(dtb[p]);
  __syncthreads();
  for (int off = 1; off < Q; off <<= 1) {
    float v = (tid >= off) ? sc[tid - off] : 0.f;
    __syncthreads();
    if (tid >= off) sc[tid] += v;
    __syncthreads();
  }
  cs_g[p] = sc[tid];
  const float cl = sc[Q-1];
  if (tid == 0) achunk[g] = expf(cl);

  const int w = tid >> 6, l = tid & 63;
  const int lrow = l & 15, lk = l >> 4;
  const int tj = tid & 63, tcb = (tid >> 6) * 16;
  f32x4 acc[4];
  { f32x4 z = {0,0,0,0}; acc[0]=z; acc[1]=z; acc[2]=z; acc[3]=z; }

  for (int js = 0; js < 4; js++) {
    __syncthreads();
    {
      const int jc = js*64 + tj;
      const float wj = expf(cl - sc[jc]);
      const size_t prow = ((size_t)g*Q + jc) * 64;
      union { uint4 v; u16 s[8]; } b0, b1, x0, x1;
      b0.v = *(const uint4*)&Bb[prow + tcb];
      b1.v = *(const uint4*)&Bb[prow + tcb + 8];
      x0.v = *(const uint4*)&inp[prow + tcb];
      x1.v = *(const uint4*)&inp[prow + tcb + 8];
      #pragma unroll
      for (int q = 0; q < 8; q++) {
        const int r0 = tcb + q, r1 = tcb + 8 + q;
        *(u16*)((char*)sBt + swz_off(r0, 2*tj)) = f2bf(wj * bf2f((u32)b0.s[q]));
        *(u16*)((char*)sBt + swz_off(r1, 2*tj)) = f2bf(wj * bf2f((u32)b1.s[q]));
        *(u16*)((char*)sXt + swz_off(r0, 2*tj)) = x0.s[q];
        *(u16*)((char*)sXt + swz_off(r1, 2*tj)) = x1.s[q];
      }
    }
    __syncthreads();
    short8 aX0 = frag_ld(sXt, w*16 + lrow, 0, lk);
    short8 aX1 = frag_ld(sXt, w*16 + lrow, 1, lk);
    #pragma unroll
    for (int n = 0; n < 4; n++) {
      short8 b0 = frag_ld(sBt, n*16 + lrow, 0, lk);
      short8 b1 = frag_ld(sBt, n*16 + lrow, 1, lk);
      acc[n] = __builtin_amdgcn_mfma_f32_16x16x32_bf16(aX0, b0, acc[n], 0, 0, 0);
      acc[n] = __builtin_amdgcn_mfma_f32_16x16x32_bf16(aX1, b1, acc[n], 0, 0, 0);
    }
  }
  #pragma unroll
  for (int reg = 0; reg < 4; reg++) {
    const int d = w*16 + lk*4 + reg;
    #pragma unroll
    for (int n = 0; n < 4; n++)
      states_t[(size_t)g*4096 + d*64 + n*16 + lrow] = acc[n][reg];
  }
}

__global__ __launch_bounds__(256) void ssd_scan(float* __restrict__ states,
    const float* __restrict__ achunk)
{
  const int n = blockIdx.x, tid = threadIdx.x;
  float S[16];
  #pragma unroll
  for (int k = 0; k < 16; k++) S[k] = 0.f;
  for (int c = 0; c < 16; c++) {
    const int g = n*16 + c;
    const float A = achunk[g];
    #pragma unroll
    for (int k = 0; k < 16; k++) {
      const size_t e = (size_t)g * 4096 + tid + k*256;
      const float st = states[e];
      states[e] = S[k];
      S[k] = fmaf(A, S[k], st);
    }
  }
}

__global__ __launch_bounds__(256) void ssd_diag(const u16* __restrict__ Bb,
    const u16* __restrict__ Cb, const u16* __restrict__ inp,
    const float* __restrict__ cs_g, const float* __restrict__ states_t,
    const u16* __restrict__ resb, u16* __restrict__ yb)
{
  const int g = blockIdx.y, it = blockIdx.x, tid = threadIdx.x;
  const int w = tid >> 6, l = tid & 63;
  const int lrow = l & 15, lk = l >> 4;
  const int p_base = g * Q;
  __shared__ u16 sC[64*64];
  __shared__ u16 sB[64*64];
  __shared__ u16 sX[64*64];
  __shared__ u16 sP[64*64];
  __shared__ float csi[64], csj[64];

  const int r = tid >> 2, c0 = (tid & 3) << 4;
  {
    const size_t prow = (size_t)(p_base + it*64 + r) * 64;
    uint4 v0 = *(const uint4*)&Cb[prow + c0];
    uint4 v1 = *(const uint4*)&Cb[prow + c0 + 8];
    *(uint4*)((char*)sC + swz_off(r, c0*2))      = v0;
    *(uint4*)((char*)sC + swz_off(r, c0*2 + 16)) = v1;
    if (tid < 64) csi[tid] = cs_g[p_base + it*64 + tid];
  }
  const int i0 = w * 16;
  const int xj = tid & 63, xdb = (tid >> 6) * 16;
  f32x4 accY[4];
  { f32x4 z = {0,0,0,0}; accY[0]=z; accY[1]=z; accY[2]=z; accY[3]=z; }

  for (int jt = 0; jt <= it; jt++) {
    __syncthreads();
    {
      const size_t prow = (size_t)(p_base + jt*64 + r) * 64;
      uint4 v0 = *(const uint4*)&Bb[prow + c0];
      uint4 v1 = *(const uint4*)&Bb[prow + c0 + 8];
      *(uint4*)((char*)sB + swz_off(r, c0*2))      = v0;
      *(uint4*)((char*)sB + swz_off(r, c0*2 + 16)) = v1;
      if (tid < 64) csj[tid] = cs_g[p_base + jt*64 + tid];
    }
    {
      const size_t prow = (size_t)(p_base + jt*64 + xj) * 64;
      union { uint4 v; u16 s[8]; } x0, x1;
      x0.v = *(const uint4*)&inp[prow + xdb];
      x1.v = *(const uint4*)&inp[prow + xdb + 8];
      #pragma unroll
      for (int q = 0; q < 8; q++) {
        *(u16*)((char*)sX + swz_off(xdb + q,     2*xj)) = x0.s[q];
        *(u16*)((char*)sX + swz_off(xdb + 8 + q, 2*xj)) = x1.s[q];
      }
    }
    __syncthreads();
    f32x4 sAcc[4];
    { f32x4 z = {0,0,0,0}; sAcc[0]=z; sAcc[1]=z; sAcc[2]=z; sAcc[3]=z; }
    {
      short8 aC0 = frag_ld(sC, i0 + lrow, 0, lk);
      short8 aC1 = frag_ld(sC, i0 + lrow, 1, lk);
      #pragma unroll
      for (int n = 0; n < 4; n++) {
        short8 b0 = frag_ld(sB, n*16 + lrow, 0, lk);
        short8 b1 = frag_ld(sB, n*16 + lrow, 1, lk);
        sAcc[n] = __builtin_amdgcn_mfma_f32_16x16x32_bf16(aC0, b0, sAcc[n], 0, 0, 0);
        sAcc[n] = __builtin_amdgcn_mfma_f32_16x16x32_bf16(aC1, b1, sAcc[n], 0, 0, 0);
      }
    }
    const bool full = (jt < it);
    #pragma unroll
    for (int n = 0; n < 4; n++) {
      const int j_l = n*16 + lrow;
      const float cj = csj[j_l];
      #pragma unroll
      for (int reg = 0; reg < 4; reg++) {
        const int i_l = i0 + lk*4 + reg;
        float s = 0.f;
        if (full || j_l <= i_l) s = sAcc[n][reg] * expf(csi[i_l] - cj);
        *(u16*)((char*)sP + swz_off(i_l, n*32 + 2*lrow)) = f2bf(s);
      }
    }
    {
      short8 aP0 = frag_ld(sP, i0 + lrow, 0, lk);
      short8 aP1 = frag_ld(sP, i0 + lrow, 1, lk);
      #pragma unroll
      for (int n = 0; n < 4; n++) {
        short8 x0f = frag_ld(sX, n*16 + lrow, 0, lk);
        short8 x1f = frag_ld(sX, n*16 + lrow, 1, lk);
        accY[n] = __builtin_amdgcn_mfma_f32_16x16x32_bf16(aP0, x0f, accY[n], 0, 0, 0);
        accY[n] = __builtin_amdgcn_mfma_f32_16x16x32_bf16(aP1, x1f, accY[n], 0, 0, 0);
      }
    }
  }
  __syncthreads();
  {
    const int d = tid & 63, sb = (tid >> 6) * 16;
    const float* srow = &states_t[(size_t)g*4096 + d*64 + sb];
    float4 f0 = *(const float4*)(srow);
    float4 f1 = *(const float4*)(srow + 4);
    float4 f2 = *(const float4*)(srow + 8);
    float4 f3 = *(const float4*)(srow + 12);
    union { uint4 v; u16 s[8]; } o0, o1;
    o0.s[0]=f2bf(f0.x); o0.s[1]=f2bf(f0.y); o0.s[2]=f2bf(f0.z); o0.s[3]=f2bf(f0.w);
    o0.s[4]=f2bf(f1.x); o0.s[5]=f2bf(f1.y); o0.s[6]=f2bf(f1.z); o0.s[7]=f2bf(f1.w);
    o1.s[0]=f2bf(f2.x); o1.s[1]=f2bf(f2.y); o1.s[2]=f2bf(f2.z); o1.s[3]=f2bf(f2.w);
    o1.s[4]=f2bf(f3.x); o1.s[5]=f2bf(f3.y); o1.s[6]=f2bf(f3.z); o1.s[7]=f2bf(f3.w);
    *(uint4*)((char*)sB + swz_off(d, sb*2))      = o0.v;
    *(uint4*)((char*)sB + swz_off(d, sb*2 + 16)) = o1.v;
  }
  __syncthreads();
  f32x4 accI[4];
  { f32x4 z = {0,0,0,0}; accI[0]=z; accI[1]=z; accI[2]=z; accI[3]=z; }
  {
    short8 aC0 = frag_ld(sC, i0 + lrow, 0, lk);
    short8 aC1 = frag_ld(sC, i0 + lrow, 1, lk);
    #pragma unroll
    for (int n = 0; n < 4; n++) {
      short8 s0 = frag_ld(sB, n*16 + lrow, 0, lk);
      short8 s1 = frag_ld(sB, n*16 + lrow, 1, lk);
      accI[n] = __builtin_amdgcn_mfma_f32_16x16x32_bf16(aC0, s0, accI[n], 0, 0, 0);
      accI[n] = __builtin_amdgcn_mfma_f32_16x16x32_bf16(aC1, s1, accI[n], 0, 0, 0);
    }
  }
  #pragma unroll
  for (int reg = 0; reg < 4; reg++) {
    const int i_l = i0 + lk*4 + reg;
    const float ei = expf(csi[i_l]);
    const size_t prow = (size_t)(p_base + it*64 + i_l) * 64;
    #pragma unroll
    for (int n = 0; n < 4; n++) {
      const int d = n*16 + lrow;
      const float yv = accY[n][reg] + ei * accI[n][reg];
      const float rv = bf2f((u32)resb[prow + d]);
      yb[prow + d] = f2bf(yv * siluf(rv));
    }
  }
}

extern "C" void kernel_launch(void* const* d_in, const int* in_sizes, int n_in,
                              void* d_out, int out_size, void* d_ws, size_t ws_size,
                              hipStream_t stream)
{
  const float* x       = (const float*)d_in[0];
  const float* w_in    = (const float*)d_in[1];
  const float* w_param = (const float*)d_in[2];
  const float* w_out   = (const float*)d_in[3];
  float* out = (float*)d_out;
  char* ws = (char*)d_ws;

  float* states    = (float*)(ws);                 // 16 MiB (aliases xb)
  u16*   xb        = (u16*)  (ws);                 // 16 MiB
  u16*   yb        = (u16*)  (ws + 0x1000000ull);  // 32 MiB (aliases w_in_b)
  u16*   w_in_b    = (u16*)  (ws + 0x1000000ull);  // 32 MiB
  u16*   w_param_b = (u16*)  (ws + 0x3000000ull);  // 8448*2048*2 = 33 MiB (pad rows)
  u16*   w_out_b   = (u16*)  (ws + 0x5100000ull);  // 16 MiB
  u16*   inp       = (u16*)  (ws + 0x6100000ull);  // 32 MiB
  u16*   resb      = (u16*)  (ws + 0x8100000ull);  // 32 MiB
  u16*   Bb        = (u16*)  (ws + 0xA100000ull);  // 32 MiB
  u16*   Cb        = (u16*)  (ws + 0xC100000ull);  // 32 MiB
  float* dtb       = (float*)(ws + 0xE100000ull);  // 1 MiB
  float* cs        = (float*)(ws + 0xE200000ull);  // 1 MiB
  float* achunk    = (float*)(ws + 0xE300000ull);  // 4 KiB

  cast_all<<<49280, 256, 0, stream>>>(x, w_in, w_param, w_out,
                                      xb, w_in_b, w_param_b, w_out_b);

  gemm_inpar<<<2080, 512, 0, stream>>>(xb, w_in_b, w_param_b,
                                       inp, resb, dtb, Bb, Cb);
  ssd_phaseA<<<1024, 256, 0, stream>>>(dtb, Bb, inp, cs, achunk, states);
  ssd_scan<<<64, 256, 0, stream>>>(states, achunk);
  ssd_diag<<<dim3(4, 1024), 256, 0, stream>>>(Bb, Cb, inp, cs, states, resb, yb);
  gemm_out64<<<512, 512, 0, stream>>>(yb, w_out_b, out);
}

// Round 19
// 535.883 us; speedup vs baseline: 1.0468x; 1.0219x over previous
//
#include <hip/hip_runtime.h>
#include <math.h>

#define Q 256

typedef unsigned short u16;
typedef unsigned int u32;
typedef __attribute__((ext_vector_type(8))) short short8;
typedef __attribute__((ext_vector_type(4))) float f32x4;

__device__ __forceinline__ float bf2f(u32 u){
  union { float f; u32 i; } v; v.i = u << 16; return v.f;
}
__device__ __forceinline__ u16 f2bf(float f){
  union { float f; u32 i; } v; v.f = f;
  u32 r = (v.i + 0x7FFFu + ((v.i >> 16) & 1u)) >> 16;
  return (u16)r;
}
// Fast transcendentals: __expf/__logf lower to v_exp_f32/v_log_f32 paths
// (~1-2 ulp). Margin check: absmax 0.25 vs threshold 0.5675 -- negligible.
__device__ __forceinline__ float softplusf(float x){
  return x > 20.f ? x : __logf(1.f + __expf(x));
}
__device__ __forceinline__ float siluf(float x){
  return x / (1.f + __expf(-x));
}

__device__ __forceinline__ void gload_lds16(const void* g, const void* l){
  __builtin_amdgcn_global_load_lds(
    (const __attribute__((address_space(1))) void*)(uintptr_t)g,
    (__attribute__((address_space(3))) void*)(u32)(uintptr_t)l,
    16, 0, 0);
}

__device__ __forceinline__ u32 swz_off(int row, int col2){
  return (u32)(row*128 + (col2 ^ ((row & 7) << 4)));
}
__device__ __forceinline__ short8 frag_ld(const u16* buf, int row, int kk, int lk){
  return *(const short8*)((const char*)buf + row*128 + (((kk*4 + lk) ^ (row & 7)) << 4));
}

// Fused bf16 cast of all four inputs (one launch; group = 4 floats).
__global__ __launch_bounds__(256) void cast_all(const float* __restrict__ x,
    const float* __restrict__ w_in, const float* __restrict__ w_param,
    const float* __restrict__ w_out, u16* __restrict__ xb,
    u16* __restrict__ w_in_b, u16* __restrict__ w_param_b, u16* __restrict__ w_out_b)
{
  const size_t g = (size_t)blockIdx.x * 256 + threadIdx.x;
  const float* src; u16* dst; size_t off;
  if (g < 2097152)        { src = x;       dst = xb;        off = g; }
  else if (g < 6291456)   { src = w_in;    dst = w_in_b;    off = g - 2097152; }
  else if (g < 10518528)  { src = w_param; dst = w_param_b; off = g - 6291456; }
  else                    { src = w_out;   dst = w_out_b;   off = g - 10518528; }
  const float4 v = *(const float4*)(src + off*4);
  ushort4 o;
  o.x = f2bf(v.x); o.y = f2bf(v.y); o.z = f2bf(v.z); o.w = f2bf(v.w);
  *(ushort4*)(dst + off*4) = o;
}

// ------------- TLP GEMM body: 128x256 tile, 8 waves, 2 blocks/CU -----------
// Session-best configuration (r14/r15/r18): 124 regs/thread (60 VGPR + 64
// acc), 4 waves/SIMD, ~37% MfmaUtil (2-phase plain-HIP structure ceiling).
#define T256_STAGE(s_) \
  _Pragma("unroll") for (int q = 0; q < 3; q++) \
    gload_lds16(sptr[q] + (s_)*32, lds + (((s_)&1)*24576) + (q*512 + tid)*16);

#define T256_BODY(A_, B_, K_) \
  __shared__ char lds[49152]; \
  const int w = tid >> 6, l = tid & 63; \
  const int wr = w >> 2, wc = w & 3; \
  const int lr = l & 15, lk = l >> 4; \
  const u16* sptr[3]; \
  _Pragma("unroll") for (int q = 0; q < 3; q++) { \
    const int c = q*512 + tid; \
    const int r = c >> 3; \
    const int lg = (c & 7) ^ (r & 7); \
    const int lrow2 = 2*r + (lg >> 2); \
    const int kc = lg & 3; \
    sptr[q] = (lrow2 < 128) ? ((A_) + (size_t)(m0 + lrow2)*(K_) + kc*8) \
                            : ((B_) + (size_t)(n0 + (lrow2 - 128))*(K_) + kc*8); \
  } \
  const int arow0 = wr*64 + lr; \
  const int abrow = arow0 >> 1; \
  const int abase = abrow*128 + ((((arow0 & 1)*4 + lk) ^ (abrow & 7)) << 4); \
  const int brow0 = 64 + ((wc*64 + lr) >> 1); \
  const int bbase = brow0*128 + ((((lr & 1)*4 + lk) ^ (brow0 & 7)) << 4); \
  f32x4 acc[4][4]; \
  { f32x4 z = {0.f,0.f,0.f,0.f}; \
    _Pragma("unroll") for (int m = 0; m < 4; m++) \
    _Pragma("unroll") for (int n = 0; n < 4; n++) acc[m][n] = z; } \
  T256_STAGE(0) \
  asm volatile("s_waitcnt vmcnt(0)" ::: "memory"); \
  __builtin_amdgcn_s_barrier(); \
  { const int NS = (K_)/32; \
    for (int s = 0; s < NS-1; ++s) { \
      const char* sb_ = lds + ((s & 1)*24576); \
      short8 aF[4], bF[4]; \
      T256_STAGE(s+1) \
      _Pragma("unroll") for (int m = 0; m < 4; m++) \
        aF[m] = *(const short8*)(sb_ + abase + m*1024); \
      _Pragma("unroll") for (int n = 0; n < 4; n++) \
        bF[n] = *(const short8*)(sb_ + bbase + n*1024); \
      __builtin_amdgcn_s_setprio(1); \
      _Pragma("unroll") for (int m = 0; m < 4; m++) \
      _Pragma("unroll") for (int n = 0; n < 4; n++) \
        acc[m][n] = __builtin_amdgcn_mfma_f32_16x16x32_bf16(aF[m], bF[n], acc[m][n], 0, 0, 0); \
      __builtin_amdgcn_s_setprio(0); \
      asm volatile("s_waitcnt vmcnt(0)" ::: "memory"); \
      __builtin_amdgcn_s_barrier(); \
    } \
    { const char* sb_ = lds + (((K_)/32 - 1) & 1)*24576; \
      short8 aF[4], bF[4]; \
      _Pragma("unroll") for (int m = 0; m < 4; m++) \
        aF[m] = *(const short8*)(sb_ + abase + m*1024); \
      _Pragma("unroll") for (int n = 0; n < 4; n++) \
        bF[n] = *(const short8*)(sb_ + bbase + n*1024); \
      _Pragma("unroll") for (int m = 0; m < 4; m++) \
      _Pragma("unroll") for (int n = 0; n < 4; n++) \
        acc[m][n] = __builtin_amdgcn_mfma_f32_16x16x32_bf16(aF[m], bF[n], acc[m][n], 0, 0, 0); \
    } \
  }

// Fused in-proj + param-proj: one 2080-block stream.
__global__ void __launch_bounds__(512, 4) gemm_inpar(const u16* __restrict__ A,
    const u16* __restrict__ Bin, const u16* __restrict__ Bpar,
    u16* __restrict__ inp, u16* __restrict__ resb,
    float* __restrict__ dtb, u16* __restrict__ Bb, u16* __restrict__ Cb)
{
  const int tid = threadIdx.x;
  const int nwg = gridDim.x, bid = blockIdx.x;
  const int wg = (bid & 7) * (nwg >> 3) + (bid >> 3);
  const bool isPar = (wg >= 1024);
  int m0, n0;
  const u16* Bmat;
  if (!isPar) { Bmat = Bin;  m0 = (wg >> 5) * 128;        n0 = (wg & 31) * 256; }
  else        { Bmat = Bpar; const int w2 = wg - 1024;
                m0 = (w2 / 33) * 128;                      n0 = (w2 % 33) * 256; }
  T256_BODY(A, Bmat, 2048)
  if (!isPar) {
    #pragma unroll
    for (int m = 0; m < 4; m++)
      #pragma unroll
      for (int n = 0; n < 4; n++) {
        const int col = n0 + wc*64 + n*16 + lr;
        #pragma unroll
        for (int j = 0; j < 4; j++) {
          const int row = m0 + wr*64 + m*16 + lk*4 + j;
          const u16 v = f2bf(acc[m][n][j]);
          if (col < 4096) inp[(size_t)row*4096 + col] = v;
          else            resb[(size_t)row*4096 + (col - 4096)] = v;
        }
      }
  } else {
    #pragma unroll
    for (int m = 0; m < 4; m++)
      #pragma unroll
      for (int n = 0; n < 4; n++) {
        const int col = n0 + wc*64 + n*16 + lr;
        if (col < 8256) {
          const int h = col / 129, rr = col - h*129;
          #pragma unroll
          for (int j = 0; j < 4; j++) {
            const int row = m0 + wr*64 + m*16 + lk*4 + j;
            const float v = acc[m][n][j];
            if (rr == 0)      dtb[(size_t)row*64 + h] = v;
            else if (rr < 65) Bb[((size_t)row*64 + h)*64 + (rr-1)]  = f2bf(v);
            else              Cb[((size_t)row*64 + h)*64 + (rr-65)] = f2bf(v);
          }
        }
      }
  }
}

// ------------- gemm_out: 128x128 tile, K-step 64 double-buffer -------------
#define O128_STAGE(s_) \
  _Pragma("unroll") for (int q = 0; q < 4; q++) \
    gload_lds16(sptr[q] + (s_)*64, lds + (((s_)&1)*32768) + (q*512 + tid)*16);

__global__ void __launch_bounds__(512, 4) gemm_out64(const u16* __restrict__ A,
    const u16* __restrict__ B, float* __restrict__ C)
{
  __shared__ char lds[65536];
  const int tid = threadIdx.x;
  const int nwg = gridDim.x, bid = blockIdx.x;
  const int wg = (bid & 7) * (nwg >> 3) + (bid >> 3);
  const int m0 = (wg >> 4) * 128, n0 = (wg & 15) * 128;
  const int w = tid >> 6, l = tid & 63;
  const int wr = w >> 2, wc = w & 3;
  const int lr = l & 15, lk = l >> 4;
  const u16* sptr[4];
  #pragma unroll
  for (int q = 0; q < 4; q++) {
    const int c = q*512 + tid;
    const int r = c >> 3;
    const int jl = (c & 7) ^ (r & 7);
    sptr[q] = (r < 128) ? (A + (size_t)(m0 + r)*4096 + jl*8)
                        : (B + (size_t)(n0 + (r - 128))*4096 + jl*8);
  }
  const int ko0 = ((lk       ^ (lr & 7)) << 4);
  const int ko1 = (((4 + lk) ^ (lr & 7)) << 4);
  const int abase = (wr*64 + lr) * 128;
  const int bbase = (128 + wc*32 + lr) * 128;
  f32x4 acc[4][2];
  { f32x4 z = {0.f,0.f,0.f,0.f};
    #pragma unroll
    for (int m = 0; m < 4; m++)
      #pragma unroll
      for (int n = 0; n < 2; n++) acc[m][n] = z; }
  O128_STAGE(0)
  asm volatile("s_waitcnt vmcnt(0)" ::: "memory");
  __builtin_amdgcn_s_barrier();
  for (int s = 0; s < 63; ++s) {
    const char* sb_ = lds + ((s & 1)*32768);
    short8 aF[2][4], bF[2][2];
    O128_STAGE(s+1)
    #pragma unroll
    for (int m = 0; m < 4; m++) {
      aF[0][m] = *(const short8*)(sb_ + abase + m*2048 + ko0);
      aF[1][m] = *(const short8*)(sb_ + abase + m*2048 + ko1);
    }
    #pragma unroll
    for (int n = 0; n < 2; n++) {
      bF[0][n] = *(const short8*)(sb_ + bbase + n*2048 + ko0);
      bF[1][n] = *(const short8*)(sb_ + bbase + n*2048 + ko1);
    }
    __builtin_amdgcn_s_setprio(1);
    #pragma unroll
    for (int m = 0; m < 4; m++)
      #pragma unroll
      for (int n = 0; n < 2; n++)
        #pragma unroll
        for (int kk = 0; kk < 2; kk++)
          acc[m][n] = __builtin_amdgcn_mfma_f32_16x16x32_bf16(aF[kk][m], bF[kk][n], acc[m][n], 0, 0, 0);
    __builtin_amdgcn_s_setprio(0);
    asm volatile("s_waitcnt vmcnt(0)" ::: "memory");
    __builtin_amdgcn_s_barrier();
  }
  {
    const char* sb_ = lds + ((63 & 1)*32768);
    short8 aF[2][4], bF[2][2];
    #pragma unroll
    for (int m = 0; m < 4; m++) {
      aF[0][m] = *(const short8*)(sb_ + abase + m*2048 + ko0);
      aF[1][m] = *(const short8*)(sb_ + abase + m*2048 + ko1);
    }
    #pragma unroll
    for (int n = 0; n < 2; n++) {
      bF[0][n] = *(const short8*)(sb_ + bbase + n*2048 + ko0);
      bF[1][n] = *(const short8*)(sb_ + bbase + n*2048 + ko1);
    }
    #pragma unroll
    for (int m = 0; m < 4; m++)
      #pragma unroll
      for (int n = 0; n < 2; n++)
        #pragma unroll
        for (int kk = 0; kk < 2; kk++)
          acc[m][n] = __builtin_amdgcn_mfma_f32_16x16x32_bf16(aF[kk][m], bF[kk][n], acc[m][n], 0, 0, 0);
  }
  #pragma unroll
  for (int m = 0; m < 4; m++)
    #pragma unroll
    for (int n = 0; n < 2; n++) {
      const int col = n0 + wc*32 + n*16 + lr;
      #pragma unroll
      for (int j = 0; j < 4; j++)
        C[(size_t)(m0 + wr*64 + m*16 + lk*4 + j)*2048 + col] = acc[m][n][j];
    }
}

// ---------------- SSD ------------------------------------------------------
__global__ __launch_bounds__(256) void ssd_phaseA(const float* __restrict__ dtb,
    const u16* __restrict__ Bb, const u16* __restrict__ inp,
    float* __restrict__ cs_g, float* __restrict__ achunk, float* __restrict__ states_t)
{
  const int g = blockIdx.x, tid = threadIdx.x;
  const int p = g * Q + tid;
  __shared__ float sc[Q];
  __shared__ u16 sBt[64*64];
  __shared__ u16 sXt[64*64];
  sc[tid] = -softplusf(dtb[p]);
  __syncthreads();
  for (int off = 1; off < Q; off <<= 1) {
    float v = (tid >= off) ? sc[tid - off] : 0.f;
    __syncthreads();
    if (tid >= off) sc[tid] += v;
    __syncthreads();
  }
  cs_g[p] = sc[tid];
  const float cl = sc[Q-1];
  if (tid == 0) achunk[g] = __expf(cl);

  const int w = tid >> 6, l = tid & 63;
  const int lrow = l & 15, lk = l >> 4;
  const int tj = tid & 63, tcb = (tid >> 6) * 16;
  f32x4 acc[4];
  { f32x4 z = {0,0,0,0}; acc[0]=z; acc[1]=z; acc[2]=z; acc[3]=z; }

  for (int js = 0; js < 4; js++) {
    __syncthreads();
    {
      const int jc = js*64 + tj;
      const float wj = __expf(cl - sc[jc]);
      const size_t prow = ((size_t)g*Q + jc) * 64;
      union { uint4 v; u16 s[8]; } b0, b1, x0, x1;
      b0.v = *(const uint4*)&Bb[prow + tcb];
      b1.v = *(const uint4*)&Bb[prow + tcb + 8];
      x0.v = *(const uint4*)&inp[prow + tcb];
      x1.v = *(const uint4*)&inp[prow + tcb + 8];
      #pragma unroll
      for (int q = 0; q < 8; q++) {
        const int r0 = tcb + q, r1 = tcb + 8 + q;
        *(u16*)((char*)sBt + swz_off(r0, 2*tj)) = f2bf(wj * bf2f((u32)b0.s[q]));
        *(u16*)((char*)sBt + swz_off(r1, 2*tj)) = f2bf(wj * bf2f((u32)b1.s[q]));
        *(u16*)((char*)sXt + swz_off(r0, 2*tj)) = x0.s[q];
        *(u16*)((char*)sXt + swz_off(r1, 2*tj)) = x1.s[q];
      }
    }
    __syncthreads();
    short8 aX0 = frag_ld(sXt, w*16 + lrow, 0, lk);
    short8 aX1 = frag_ld(sXt, w*16 + lrow, 1, lk);
    #pragma unroll
    for (int n = 0; n < 4; n++) {
      short8 b0 = frag_ld(sBt, n*16 + lrow, 0, lk);
      short8 b1 = frag_ld(sBt, n*16 + lrow, 1, lk);
      acc[n] = __builtin_amdgcn_mfma_f32_16x16x32_bf16(aX0, b0, acc[n], 0, 0, 0);
      acc[n] = __builtin_amdgcn_mfma_f32_16x16x32_bf16(aX1, b1, acc[n], 0, 0, 0);
    }
  }
  #pragma unroll
  for (int reg = 0; reg < 4; reg++) {
    const int d = w*16 + lk*4 + reg;
    #pragma unroll
    for (int n = 0; n < 4; n++)
      states_t[(size_t)g*4096 + d*64 + n*16 + lrow] = acc[n][reg];
  }
}

__global__ __launch_bounds__(256) void ssd_scan(float* __restrict__ states,
    const float* __restrict__ achunk)
{
  const int n = blockIdx.x, tid = threadIdx.x;
  float S[16];
  #pragma unroll
  for (int k = 0; k < 16; k++) S[k] = 0.f;
  for (int c = 0; c < 16; c++) {
    const int g = n*16 + c;
    const float A = achunk[g];
    #pragma unroll
    for (int k = 0; k < 16; k++) {
      const size_t e = (size_t)g * 4096 + tid + k*256;
      const float st = states[e];
      states[e] = S[k];
      S[k] = fmaf(A, S[k], st);
    }
  }
}

__global__ __launch_bounds__(256) void ssd_diag(const u16* __restrict__ Bb,
    const u16* __restrict__ Cb, const u16* __restrict__ inp,
    const float* __restrict__ cs_g, const float* __restrict__ states_t,
    const u16* __restrict__ resb, u16* __restrict__ yb)
{
  const int g = blockIdx.y, it = blockIdx.x, tid = threadIdx.x;
  const int w = tid >> 6, l = tid & 63;
  const int lrow = l & 15, lk = l >> 4;
  const int p_base = g * Q;
  __shared__ u16 sC[64*64];
  __shared__ u16 sB[64*64];
  __shared__ u16 sX[64*64];
  __shared__ u16 sP[64*64];
  __shared__ float csi[64], csj[64];

  const int r = tid >> 2, c0 = (tid & 3) << 4;
  {
    const size_t prow = (size_t)(p_base + it*64 + r) * 64;
    uint4 v0 = *(const uint4*)&Cb[prow + c0];
    uint4 v1 = *(const uint4*)&Cb[prow + c0 + 8];
    *(uint4*)((char*)sC + swz_off(r, c0*2))      = v0;
    *(uint4*)((char*)sC + swz_off(r, c0*2 + 16)) = v1;
    if (tid < 64) csi[tid] = cs_g[p_base + it*64 + tid];
  }
  const int i0 = w * 16;
  const int xj = tid & 63, xdb = (tid >> 6) * 16;
  f32x4 accY[4];
  { f32x4 z = {0,0,0,0}; accY[0]=z; accY[1]=z; accY[2]=z; accY[3]=z; }

  for (int jt = 0; jt <= it; jt++) {
    __syncthreads();
    {
      const size_t prow = (size_t)(p_base + jt*64 + r) * 64;
      uint4 v0 = *(const uint4*)&Bb[prow + c0];
      uint4 v1 = *(const uint4*)&Bb[prow + c0 + 8];
      *(uint4*)((char*)sB + swz_off(r, c0*2))      = v0;
      *(uint4*)((char*)sB + swz_off(r, c0*2 + 16)) = v1;
      if (tid < 64) csj[tid] = cs_g[p_base + jt*64 + tid];
    }
    {
      const size_t prow = (size_t)(p_base + jt*64 + xj) * 64;
      union { uint4 v; u16 s[8]; } x0, x1;
      x0.v = *(const uint4*)&inp[prow + xdb];
      x1.v = *(const uint4*)&inp[prow + xdb + 8];
      #pragma unroll
      for (int q = 0; q < 8; q++) {
        *(u16*)((char*)sX + swz_off(xdb + q,     2*xj)) = x0.s[q];
        *(u16*)((char*)sX + swz_off(xdb + 8 + q, 2*xj)) = x1.s[q];
      }
    }
    __syncthreads();
    f32x4 sAcc[4];
    { f32x4 z = {0,0,0,0}; sAcc[0]=z; sAcc[1]=z; sAcc[2]=z; sAcc[3]=z; }
    {
      short8 aC0 = frag_ld(sC, i0 + lrow, 0, lk);
      short8 aC1 = frag_ld(sC, i0 + lrow, 1, lk);
      #pragma unroll
      for (int n = 0; n < 4; n++) {
        short8 b0 = frag_ld(sB, n*16 + lrow, 0, lk);
        short8 b1 = frag_ld(sB, n*16 + lrow, 1, lk);
        sAcc[n] = __builtin_amdgcn_mfma_f32_16x16x32_bf16(aC0, b0, sAcc[n], 0, 0, 0);
        sAcc[n] = __builtin_amdgcn_mfma_f32_16x16x32_bf16(aC1, b1, sAcc[n], 0, 0, 0);
      }
    }
    const bool full = (jt < it);
    #pragma unroll
    for (int n = 0; n < 4; n++) {
      const int j_l = n*16 + lrow;
      const float cj = csj[j_l];
      #pragma unroll
      for (int reg = 0; reg < 4; reg++) {
        const int i_l = i0 + lk*4 + reg;
        float s = 0.f;
        if (full || j_l <= i_l) s = sAcc[n][reg] * __expf(csi[i_l] - cj);
        *(u16*)((char*)sP + swz_off(i_l, n*32 + 2*lrow)) = f2bf(s);
      }
    }
    {
      short8 aP0 = frag_ld(sP, i0 + lrow, 0, lk);
      short8 aP1 = frag_ld(sP, i0 + lrow, 1, lk);
      #pragma unroll
      for (int n = 0; n < 4; n++) {
        short8 x0f = frag_ld(sX, n*16 + lrow, 0, lk);
        short8 x1f = frag_ld(sX, n*16 + lrow, 1, lk);
        accY[n] = __builtin_amdgcn_mfma_f32_16x16x32_bf16(aP0, x0f, accY[n], 0, 0, 0);
        accY[n] = __builtin_amdgcn_mfma_f32_16x16x32_bf16(aP1, x1f, accY[n], 0, 0, 0);
      }
    }
  }
  __syncthreads();
  {
    const int d = tid & 63, sb = (tid >> 6) * 16;
    const float* srow = &states_t[(size_t)g*4096 + d*64 + sb];
    float4 f0 = *(const float4*)(srow);
    float4 f1 = *(const float4*)(srow + 4);
    float4 f2 = *(const float4*)(srow + 8);
    float4 f3 = *(const float4*)(srow + 12);
    union { uint4 v; u16 s[8]; } o0, o1;
    o0.s[0]=f2bf(f0.x); o0.s[1]=f2bf(f0.y); o0.s[2]=f2bf(f0.z); o0.s[3]=f2bf(f0.w);
    o0.s[4]=f2bf(f1.x); o0.s[5]=f2bf(f1.y); o0.s[6]=f2bf(f1.z); o0.s[7]=f2bf(f1.w);
    o1.s[0]=f2bf(f2.x); o1.s[1]=f2bf(f2.y); o1.s[2]=f2bf(f2.z); o1.s[3]=f2bf(f2.w);
    o1.s[4]=f2bf(f3.x); o1.s[5]=f2bf(f3.y); o1.s[6]=f2bf(f3.z); o1.s[7]=f2bf(f3.w);
    *(uint4*)((char*)sB + swz_off(d, sb*2))      = o0.v;
    *(uint4*)((char*)sB + swz_off(d, sb*2 + 16)) = o1.v;
  }
  __syncthreads();
  f32x4 accI[4];
  { f32x4 z = {0,0,0,0}; accI[0]=z; accI[1]=z; accI[2]=z; accI[3]=z; }
  {
    short8 aC0 = frag_ld(sC, i0 + lrow, 0, lk);
    short8 aC1 = frag_ld(sC, i0 + lrow, 1, lk);
    #pragma unroll
    for (int n = 0; n < 4; n++) {
      short8 s0 = frag_ld(sB, n*16 + lrow, 0, lk);
      short8 s1 = frag_ld(sB, n*16 + lrow, 1, lk);
      accI[n] = __builtin_amdgcn_mfma_f32_16x16x32_bf16(aC0, s0, accI[n], 0, 0, 0);
      accI[n] = __builtin_amdgcn_mfma_f32_16x16x32_bf16(aC1, s1, accI[n], 0, 0, 0);
    }
  }
  #pragma unroll
  for (int reg = 0; reg < 4; reg++) {
    const int i_l = i0 + lk*4 + reg;
    const float ei = __expf(csi[i_l]);
    const size_t prow = (size_t)(p_base + it*64 + i_l) * 64;
    #pragma unroll
    for (int n = 0; n < 4; n++) {
      const int d = n*16 + lrow;
      const float yv = accY[n][reg] + ei * accI[n][reg];
      const float rv = bf2f((u32)resb[prow + d]);
      yb[prow + d] = f2bf(yv * siluf(rv));
    }
  }
}

extern "C" void kernel_launch(void* const* d_in, const int* in_sizes, int n_in,
                              void* d_out, int out_size, void* d_ws, size_t ws_size,
                              hipStream_t stream)
{
  const float* x       = (const float*)d_in[0];
  const float* w_in    = (const float*)d_in[1];
  const float* w_param = (const float*)d_in[2];
  const float* w_out   = (const float*)d_in[3];
  float* out = (float*)d_out;
  char* ws = (char*)d_ws;

  float* states    = (float*)(ws);                 // 16 MiB (aliases xb)
  u16*   xb        = (u16*)  (ws);                 // 16 MiB
  u16*   yb        = (u16*)  (ws + 0x1000000ull);  // 32 MiB (aliases w_in_b)
  u16*   w_in_b    = (u16*)  (ws + 0x1000000ull);  // 32 MiB
  u16*   w_param_b = (u16*)  (ws + 0x3000000ull);  // 8448*2048*2 = 33 MiB (pad rows)
  u16*   w_out_b   = (u16*)  (ws + 0x5100000ull);  // 16 MiB
  u16*   inp       = (u16*)  (ws + 0x6100000ull);  // 32 MiB
  u16*   resb      = (u16*)  (ws + 0x8100000ull);  // 32 MiB
  u16*   Bb        = (u16*)  (ws + 0xA100000ull);  // 32 MiB
  u16*   Cb        = (u16*)  (ws + 0xC100000ull);  // 32 MiB
  float* dtb       = (float*)(ws + 0xE100000ull);  // 1 MiB
  float* cs        = (float*)(ws + 0xE200000ull);  // 1 MiB
  float* achunk    = (float*)(ws + 0xE300000ull);  // 4 KiB

  cast_all<<<49280, 256, 0, stream>>>(x, w_in, w_param, w_out,
                                      xb, w_in_b, w_param_b, w_out_b);

  gemm_inpar<<<2080, 512, 0, stream>>>(xb, w_in_b, w_param_b,
                                       inp, resb, dtb, Bb, Cb);
  ssd_phaseA<<<1024, 256, 0, stream>>>(dtb, Bb, inp, cs, achunk, states);
  ssd_scan<<<64, 256, 0, stream>>>(states, achunk);
  ssd_diag<<<dim3(4, 1024), 256, 0, stream>>>(Bb, Cb, inp, cs, states, resb, yb);
  gemm_out64<<<512, 512, 0, stream>>>(yb, w_out_b, out);
}